// Round 9
// baseline (228.773 us; speedup 1.0000x reference)
//
#include <hip/hip_runtime.h>

// Multihead self-attention with 3-scale relative positional embeddings.
// B=4, S=1024, D=512, H=8, HD=64.  Outputs: out (4,1024,512) f32, attn (4,8,1024,1024) f32.
//
// Skew algebra (verified round 1):
//   Srel_q[i,j]  = q[i] . Er_q[1023 + j - i]
//   Srel_b[i,j]  = q[i] . Er_b[255 + (j>>2) - (i>>2)]
//   Srel_r[i,j]  = q[i] . Er_r[63  + (j>>4) - (i>>4)]
//
// Round-9: 2 blocks/CU (TLP covers store drains + load latency).
// 512 blocks x 64-row chunks, 4 strips of 16. LDS 77.3KB: PACC overlays dead
// RQ2; next strip's RQ2 built into current PS region (per-wave col ownership,
// after own-wave bfrag reads). Non-temporal attn/out stores. 3 syncthreads/strip.

typedef float f32x4 __attribute__((ext_vector_type(4)));
typedef short s16x8 __attribute__((ext_vector_type(8)));
typedef short s16x4 __attribute__((ext_vector_type(4)));
typedef __bf16 bf16x8 __attribute__((ext_vector_type(8)));

static __device__ __forceinline__ short f2bf(float f) {
    return __builtin_bit_cast(short, (__bf16)f);
}
static __device__ __forceinline__ float bf2f(short s) {
    union { unsigned u; float f; } v;
    v.u = ((unsigned)(unsigned short)s) << 16;
    return v.f;
}
static __device__ __forceinline__ f32x4 MM(s16x8 a, s16x8 b, f32x4 c) {
    return __builtin_amdgcn_mfma_f32_16x16x32_bf16(
        __builtin_bit_cast(bf16x8, a), __builtin_bit_cast(bf16x8, b), c, 0, 0, 0);
}

// ---------------------------------------------------------------------------
// K0: one-shot f32 -> bf16 conversion of all reused operands.
// ---------------------------------------------------------------------------
struct CvtArgs {
    const float* src[9];
    short* dst[9];
    unsigned n[9];
};

__global__ __launch_bounds__(256) void convert_kernel(CvtArgs a) {
    const int ai = blockIdx.y;
    const unsigned n = a.n[ai];
    const float* __restrict__ s = a.src[ai];
    short* __restrict__ d = a.dst[ai];
    const unsigned stride = gridDim.x * 256 * 8;
    for (unsigned base = (blockIdx.x * 256 + threadIdx.x) * 8; base < n; base += stride) {
        f32x4 v0 = *(const f32x4*)(s + base);
        f32x4 v1 = *(const f32x4*)(s + base + 4);
        s16x8 o;
        o[0] = f2bf(v0[0]); o[1] = f2bf(v0[1]); o[2] = f2bf(v0[2]); o[3] = f2bf(v0[3]);
        o[4] = f2bf(v1[0]); o[5] = f2bf(v1[1]); o[6] = f2bf(v1[2]); o[7] = f2bf(v1[3]);
        *(s16x8*)(d + base) = o;
    }
}

// ---------------------------------------------------------------------------
// K1: QKV projections, 64x64 wave tiles, swapped operands -> vector b64 stores.
// ---------------------------------------------------------------------------
__global__ __launch_bounds__(128, 2) void proj_kernel(
    const short* __restrict__ queryb, const short* __restrict__ keyb, const short* __restrict__ valueb,
    const short* __restrict__ Wqb, const float* __restrict__ bq,
    const short* __restrict__ Wkb, const float* __restrict__ bk,
    const short* __restrict__ Wvb, const float* __restrict__ bv,
    short* __restrict__ qb, short* __restrict__ kb, short* __restrict__ vT)
{
    const int tid = threadIdx.x;
    const int wid = tid >> 6, lane = tid & 63;
    const int l15 = lane & 15, grp = lane >> 4;
    const int gid = blockIdx.x * 2 + wid;     // 0..1535
    const int z = gid >> 9;                   // 0,1,2
    const int r = gid & 511;

    const short *Am, *Bm;
    const float* bias;
    int a0, b0;
    if (z == 0)      { Am = Wqb;    Bm = queryb; bias = bq; a0 = (r >> 6) * 64; b0 = (r & 63) * 64; }
    else if (z == 1) { Am = Wkb;    Bm = keyb;   bias = bk; a0 = (r >> 6) * 64; b0 = (r & 63) * 64; }
    else             { Am = valueb; Bm = Wvb;    bias = bv; a0 = (r >> 3) * 64; b0 = (r & 7) * 64; }

    f32x4 acc[4][4];
    #pragma unroll
    for (int i = 0; i < 4; ++i)
        #pragma unroll
        for (int j = 0; j < 4; ++j)
            acc[i][j] = f32x4{0.f, 0.f, 0.f, 0.f};

    const short* arow0 = Am + (size_t)(a0 + l15) * 512 + grp * 8;
    const short* brow0 = Bm + (size_t)(b0 + l15) * 512 + grp * 8;

    s16x8 aA[4], bA[4], aB[4], bB[4];
    #pragma unroll
    for (int i = 0; i < 4; ++i) {
        aA[i] = *(const s16x8*)(arow0 + (size_t)i * 16 * 512);
        bA[i] = *(const s16x8*)(brow0 + (size_t)i * 16 * 512);
    }
    for (int kk = 0; kk < 512; kk += 32) {
        const int kn = kk + 32;
        if (kn < 512) {
            #pragma unroll
            for (int i = 0; i < 4; ++i) {
                aB[i] = *(const s16x8*)(arow0 + (size_t)i * 16 * 512 + kn);
                bB[i] = *(const s16x8*)(brow0 + (size_t)i * 16 * 512 + kn);
            }
        }
        #pragma unroll
        for (int i = 0; i < 4; ++i)
            #pragma unroll
            for (int j = 0; j < 4; ++j)
                acc[i][j] = MM(aA[i], bA[j], acc[i][j]);
        #pragma unroll
        for (int i = 0; i < 4; ++i) { aA[i] = aB[i]; bA[i] = bB[i]; }
    }

    if (z < 2) {
        short* dst = (z == 0) ? qb : kb;
        #pragma unroll
        for (int i = 0; i < 4; ++i) {
            const int f0 = a0 + i * 16 + grp * 4;
            const f32x4 bv4 = *(const f32x4*)&bias[f0];
            const int h = f0 >> 6, d0 = f0 & 63;
            #pragma unroll
            for (int j = 0; j < 4; ++j) {
                const int srow = b0 + j * 16 + l15;
                const int bb = srow >> 10, sl = srow & 1023;
                s16x4 o;
                #pragma unroll
                for (int g = 0; g < 4; ++g)
                    o[g] = f2bf(acc[i][j][g] + bv4[g]);
                *(s16x4*)&dst[(size_t)((bb * 8 + h) * 1024 + sl) * 64 + d0] = o;
            }
        }
    } else {
        #pragma unroll
        for (int j = 0; j < 4; ++j) {
            const int n = b0 + j * 16 + l15;
            const float bval = bias[n];
            const int h = n >> 6, d = n & 63;
            #pragma unroll
            for (int i = 0; i < 4; ++i) {
                const int s0 = a0 + i * 16 + grp * 4;
                const int bb = s0 >> 10, sl = s0 & 1023;
                s16x4 o;
                #pragma unroll
                for (int g = 0; g < 4; ++g)
                    o[g] = f2bf(acc[i][j][g] + bval);
                *(s16x4*)&vT[(size_t)((bb * 8 + h) * 64 + d) * 1024 + sl] = o;
            }
        }
    }
}

// ---------------------------------------------------------------------------
// K2: fused relative attention, 2 blocks/CU.
// Grid 512 x 512thr; block = (b,h, 64-row chunk), 4 strips of 16 rows.
// Thread (wid,grp,l15): P[i=l15][j = wid*128 + t*16 + grp*4 + g].
// LDS 77312B:
//   region A @ 0      (32896B)  \  alternate roles per strip parity:
//   region B @ 32896  (32896B)  /  RQ2(s) [16][1028]bf16 (PACC [8][1028]f32
//                                  overlays after loop1) vs PS(s) [16][1028]
//                                  (buildT(s+1) writes RQ2' into PS region,
//                                   per-wave col slice, after bfrag reads)
//   RB2 @ 65792 [16][260] bf16 (8320B)
//   RR2 @ 74112 [16][68]  bf16 (2176B)
//   RSUM @ 76288 [2][16][8] f32 (1024B, strip-parity buffered)
// ---------------------------------------------------------------------------
__global__ __launch_bounds__(512, 4) void attn_kernel(
    const short* __restrict__ Eqb, const short* __restrict__ Ebb, const short* __restrict__ Errb,
    const short* __restrict__ qb, const short* __restrict__ kb, const short* __restrict__ vT,
    float* __restrict__ out, float* __restrict__ attn)
{
    __shared__ __align__(16) char smem[77312];

    const int tid = threadIdx.x;
    const int wid = tid >> 6, lane = tid & 63;
    const int l15 = lane & 15, grp = lane >> 4;

    // XCD-aware bijective swizzle: 512 blocks, XCD x -> data-bids 64x..64x+63
    // (= 4 whole bh per XCD -> K/V panels L2-resident).
    const int orig = blockIdx.x;
    const int bid = (orig & 7) * 64 + (orig >> 3);

    const int bh = bid >> 4;                 // b*8+h
    const int chunk = bid & 15;              // 64-row chunk
    const int h = bh & 7;
    const int b = bh >> 3;

    const short* EqH = Eqb  + (size_t)h * 2047 * 64;
    const short* EbH = Ebb  + (size_t)h * 511 * 64;
    const short* ErH = Errb + (size_t)h * 127 * 64;
    const short* qbH = qb + (size_t)bh * 1024 * 64;
    const short* kbH = kb + (size_t)bh * 1024 * 64;
    const short* vTH = vT + (size_t)bh * 64 * 1024;

    short* RB2 = (short*)(smem + 65792);
    short* RR2 = (short*)(smem + 74112);

    // ---- table builder: RQ2 -> given region with per-wave col ownership
    //      (wave w writes exactly j in [w*128, w*128+128) = its PS slice) ----
    auto buildT = [&](int i0s, char* regRQ, s16x8 q0, s16x8 q1) {
        short* RQ2 = (short*)regRQ;
        const int qbase = 1008 - i0s;        // >= 0 for all call sites
        {
            auto ldq = [&](int cs, s16x8& e0, s16x8& e1) {
                int erow = qbase + wid * 128 + cs * 16 + l15;
                if (erow > 2046) erow = 2046;
                const short* ep = EqH + (size_t)erow * 64 + grp * 8;
                e0 = *(const s16x8*)ep;
                e1 = *(const s16x8*)(ep + 32);
            };
            s16x8 A0, A1, B0, B1;
            ldq(0, A0, A1);
            ldq(1, B0, B1);
            for (int cs = 0; cs < 9; ++cs) {
                f32x4 a = f32x4{0.f, 0.f, 0.f, 0.f};
                a = MM(q0, A0, a);
                a = MM(q1, A1, a);
                A0 = B0; A1 = B1;
                if (cs < 8) ldq(cs + 2, B0, B1);
                const int c = wid * 128 + cs * 16 + l15;
                #pragma unroll
                for (int g = 0; g < 4; ++g) {
                    const int ii = grp * 4 + g;
                    const int j = c - 15 + ii;
                    if (j >= wid * 128 && j < wid * 128 + 128 && j < 1024)
                        RQ2[ii * 1028 + j] = f2bf(a[g]);
                }
            }
        }
        const int bbase = 252 - (i0s >> 2);
        {
            auto ldb = [&](int cs, s16x8& e0, s16x8& e1) {
                int erow = bbase + cs * 16 + l15;
                if (erow > 510) erow = 510;
                const short* ep = EbH + (size_t)erow * 64 + grp * 8;
                e0 = *(const s16x8*)ep;
                e1 = *(const s16x8*)(ep + 32);
            };
            s16x8 A0, A1, B0, B1;
            ldb(wid, A0, A1);
            ldb(wid + 8, B0, B1);
            for (int cs = wid; cs < 17; cs += 8) {
                f32x4 a = f32x4{0.f, 0.f, 0.f, 0.f};
                a = MM(q0, A0, a);
                a = MM(q1, A1, a);
                A0 = B0; A1 = B1;
                ldb(cs + 16, B0, B1);
                const int c = cs * 16 + l15;
                const int jq = c - 3 + grp;
                if (jq >= 0 && jq < 256) {
                    #pragma unroll
                    for (int g = 0; g < 4; ++g)
                        RB2[(grp * 4 + g) * 260 + jq] = f2bf(a[g]);
                }
            }
        }
        const int rbase = 63 - (i0s >> 4);
        if (wid < 4) {
            const int c = wid * 16 + l15;
            const short* ep = ErH + (size_t)(rbase + c) * 64 + grp * 8;
            s16x8 e0 = *(const s16x8*)ep;
            s16x8 e1 = *(const s16x8*)(ep + 32);
            f32x4 a = f32x4{0.f, 0.f, 0.f, 0.f};
            a = MM(q0, e0, a);
            a = MM(q1, e1, a);
            #pragma unroll
            for (int g = 0; g < 4; ++g)
                RR2[(grp * 4 + g) * 68 + c] = f2bf(a[g]);
        }
    };

    // ---- prologue: q(strip0), build tables for strip 0 into region A ----
    const int i00 = chunk * 64;
    s16x8 qA0 = *(const s16x8*)(qbH + (size_t)(i00 + l15) * 64 + grp * 8);
    s16x8 qA1 = *(const s16x8*)(qbH + (size_t)(i00 + l15) * 64 + 32 + grp * 8);
    buildT(i00, smem, qA0, qA1);
    __syncthreads();

    const float SC = 0.125f * 1.4426950408889634f;   // 1/sqrt(64) * log2(e)
    const int swz = (l15 & 3) << 5;                  // PS col XOR swizzle

    for (int s = 0; s < 4; ++s) {
        const int i0 = i00 + s * 16;
        char* tabR = smem + ((s & 1) ? 32896 : 0);   // RQ2(s); PACC overlays
        char* psR  = smem + ((s & 1) ? 0 : 32896);   // PS(s); RQ2(s+1) target
        short* RQ2c = (short*)tabR;
        short* PSc  = (short*)psR;
        float* RSUMp = (float*)(smem + 76288) + (s & 1) * 128;

        // ---- K fragment loads (fresh each strip; L2-hot) + next-q prefetch ----
        s16x8 kf[8][2];
        #pragma unroll
        for (int t = 0; t < 8; ++t) {
            const short* kp = kbH + (size_t)(wid * 128 + t * 16 + l15) * 64 + grp * 8;
            kf[t][0] = *(const s16x8*)kp;
            kf[t][1] = *(const s16x8*)(kp + 32);
        }
        s16x8 qn0, qn1;
        if (s < 3) {
            qn0 = *(const s16x8*)(qbH + (size_t)(i0 + 16 + l15) * 64 + grp * 8);
            qn1 = *(const s16x8*)(qbH + (size_t)(i0 + 16 + l15) * 64 + 32 + grp * 8);
        }

        // ---- loop1: QK^T (swapped) + vector gathers + exp2 -> p (unnormalized) ----
        f32x4 p[8];
        #pragma unroll
        for (int t = 0; t < 8; ++t) {
            f32x4 a = f32x4{0.f, 0.f, 0.f, 0.f};
            a = MM(kf[t][0], qA0, a);
            a = MM(kf[t][1], qA1, a);
            const int jb2 = wid * 128 + t * 16 + grp * 4;
            s16x4 gq4 = *(const s16x4*)&RQ2c[l15 * 1028 + jb2];
            const float rb = bf2f(RB2[l15 * 260 + wid * 32 + t * 4 + grp]);
            const float rr = bf2f(RR2[l15 * 68 + wid * 8 + t]);
            const float add = rb + rr;
            f32x4 pe;
            #pragma unroll
            for (int g = 0; g < 4; ++g)
                pe[g] = __builtin_amdgcn_exp2f((a[g] + bf2f(gq4[g]) + add) * SC);
            p[t] = pe;
        }

        // ---- rowsum partial -> RSUM[parity] ----
        float part = 0.f;
        #pragma unroll
        for (int t = 0; t < 8; ++t)
            #pragma unroll
            for (int g = 0; g < 4; ++g)
                part += p[t][g];
        part += __shfl_xor(part, 16, 64);
        part += __shfl_xor(part, 32, 64);
        if (lane < 16) RSUMp[lane * 8 + wid] = part;

        // ---- stage unnormalized bf16 P into own PS slice (swizzled b64) ----
        #pragma unroll
        for (int t = 0; t < 8; ++t) {
            const int col = (wid * 128 + t * 16 + grp * 4) ^ swz;
            s16x4 o;
            #pragma unroll
            for (int g = 0; g < 4; ++g) o[g] = f2bf(p[t][g]);
            *(s16x4*)&PSc[l15 * 1028 + col] = o;
        }
        __syncthreads();                              // BAR1: RSUM+PS visible; RQ2 dead

        // ---- V fragment loads (oldest vmem this phase -> PV not store-blocked) ----
        s16x8 vreg[16];
        #pragma unroll
        for (int dvt = 0; dvt < 4; ++dvt)
            #pragma unroll
            for (int kc = 0; kc < 4; ++kc)
                vreg[dvt * 4 + kc] = *(const s16x8*)(vTH + (size_t)(dvt * 16 + l15) * 1024
                                                     + wid * 128 + kc * 32 + grp * 8);

        // ---- rinv + bfrag reads (own PS slice, BEFORE buildT overwrites it) ----
        float rinv;
        {
            f32x4 s0 = *(const f32x4*)&RSUMp[l15 * 8];
            f32x4 s1 = *(const f32x4*)&RSUMp[l15 * 8 + 4];
            rinv = 1.0f / (s0[0] + s0[1] + s0[2] + s0[3] + s1[0] + s1[1] + s1[2] + s1[3]);
        }
        s16x8 bfrag[4];
        #pragma unroll
        for (int kc = 0; kc < 4; ++kc) {
            const int col = (wid * 128 + kc * 32 + grp * 8) ^ swz;
            bfrag[kc] = *(const s16x8*)&PSc[l15 * 1028 + col];
        }

        // ---- build next strip's tables into PS region (own col slice only) ----
        if (s < 3) buildT(i0 + 16, psR, qn0, qn1);

        // ---- attn store from regs (non-temporal; drains across strip) ----
        {
            float* arow = attn + (size_t)(bh * 1024 + i0 + l15) * 1024;
            #pragma unroll
            for (int t = 0; t < 8; ++t) {
                f32x4 o = p[t] * rinv;
                __builtin_nontemporal_store(o, (f32x4*)&arow[wid * 128 + t * 16 + grp * 4]);
            }
        }

        // ---- PV (bfrag regs x vreg) -> PACC over dead RQ2 region (swizzled) ----
        f32x4 acc[4];
        #pragma unroll
        for (int dvt = 0; dvt < 4; ++dvt) acc[dvt] = f32x4{0.f, 0.f, 0.f, 0.f};
        #pragma unroll
        for (int kc = 0; kc < 4; ++kc)
            #pragma unroll
            for (int dvt = 0; dvt < 4; ++dvt)
                acc[dvt] = MM(vreg[dvt * 4 + kc], bfrag[kc], acc[dvt]);
        float* PACC = (float*)tabR;
        #pragma unroll
        for (int dvt = 0; dvt < 4; ++dvt)
            *(f32x4*)&PACC[wid * 1028 + l15 * 64 + ((dvt * 16 + grp * 4) ^ ((l15 & 7) << 3))] = acc[dvt];
        __syncthreads();                              // BAR2: PACC + tables visible

        // ---- out-reduce (waves 0-3) -> nt store ----
        if (tid < 256) {
            const int i = tid >> 4, dvq = tid & 15;
            f32x4 o = f32x4{0.f, 0.f, 0.f, 0.f};
            #pragma unroll
            for (int w = 0; w < 8; ++w)
                o += *(const f32x4*)&PACC[w * 1028 + i * 64 + ((dvq * 4) ^ ((i & 7) << 3))];
            f32x4 s0 = *(const f32x4*)&RSUMp[i * 8];
            f32x4 s1 = *(const f32x4*)&RSUMp[i * 8 + 4];
            const float ri = 1.0f / (s0[0] + s0[1] + s0[2] + s0[3] + s1[0] + s1[1] + s1[2] + s1[3]);
            o *= ri;
            __builtin_nontemporal_store(o, (f32x4*)&out[(size_t)(b * 1024 + i0 + i) * 512 + h * 64 + dvq * 4]);
        }
        __syncthreads();                              // BAR3: PACC dead -> reusable as PS(s+1)

        if (s < 3) { qA0 = qn0; qA1 = qn1; }
    }
}

// ---------------------------------------------------------------------------
extern "C" void kernel_launch(void* const* d_in, const int* in_sizes, int n_in,
                              void* d_out, int out_size, void* d_ws, size_t ws_size,
                              hipStream_t stream)
{
    const float* query = (const float*)d_in[0];
    const float* key   = (const float*)d_in[1];
    const float* value = (const float*)d_in[2];
    const float* Wq = (const float*)d_in[3];
    const float* bq = (const float*)d_in[4];
    const float* Wk = (const float*)d_in[5];
    const float* bk = (const float*)d_in[6];
    const float* Wv = (const float*)d_in[7];
    const float* bv = (const float*)d_in[8];
    const float* Eq = (const float*)d_in[9];
    const float* Eb = (const float*)d_in[10];
    const float* Er = (const float*)d_in[11];

    float* out  = (float*)d_out;
    float* attn = out + (size_t)4 * 1024 * 512;

    short* qb     = (short*)d_ws;
    short* kb     = qb     + 2097152;
    short* vT     = kb     + 2097152;
    short* queryb = vT     + 2097152;
    short* keyb   = queryb + 2097152;
    short* valueb = keyb   + 2097152;
    short* Wqb    = valueb + 2097152;
    short* Wkb    = Wqb    + 262144;
    short* Wvb    = Wkb    + 262144;
    short* Eqb    = Wvb    + 262144;
    short* Ebb    = Eqb    + 1048064;   // 8*2047*64
    short* Errb   = Ebb    + 261632;    // 8*511*64

    CvtArgs a;
    a.src[0] = query; a.dst[0] = queryb; a.n[0] = 2097152;
    a.src[1] = key;   a.dst[1] = keyb;   a.n[1] = 2097152;
    a.src[2] = value; a.dst[2] = valueb; a.n[2] = 2097152;
    a.src[3] = Wq;    a.dst[3] = Wqb;    a.n[3] = 262144;
    a.src[4] = Wk;    a.dst[4] = Wkb;    a.n[4] = 262144;
    a.src[5] = Wv;    a.dst[5] = Wvb;    a.n[5] = 262144;
    a.src[6] = Eq;    a.dst[6] = Eqb;    a.n[6] = 1048064;
    a.src[7] = Eb;    a.dst[7] = Ebb;    a.n[7] = 261632;
    a.src[8] = Er;    a.dst[8] = Errb;   a.n[8] = 65024;

    convert_kernel<<<dim3(128, 9), 256, 0, stream>>>(a);
    proj_kernel<<<768, 128, 0, stream>>>(queryb, keyb, valueb,
                                         Wqb, bq, Wkb, bk, Wvb, bv, qb, kb, vT);
    attn_kernel<<<512, 512, 0, stream>>>(Eqb, Ebb, Errb, qb, kb, vT, out, attn);
}

// Round 10
// 185.565 us; speedup vs baseline: 1.2328x; 1.2328x over previous
//
#include <hip/hip_runtime.h>

// Multihead self-attention with 3-scale relative positional embeddings.
// B=4, S=1024, D=512, H=8, HD=64.  Outputs: out (4,1024,512) f32, attn (4,8,1024,1024) f32.
//
// Skew algebra (verified round 1):
//   Srel_q[i,j]  = q[i] . Er_q[1023 + j - i]
//   Srel_b[i,j]  = q[i] . Er_b[255 + (j>>2) - (i>>2)]
//   Srel_r[i,j]  = q[i] . Er_r[63  + (j>>4) - (i>>4)]
//
// Round-10: split attn into two streaming kernels.
//   K2A: softmax -> normalized f32 attn (1 barrier, wave-private tables)
//   K2B: PV from attn (L3-resident) -> out (1 barrier)
// No non-temporal stores (R9: nt caused 2.4x write amp + RMW fills).

typedef float f32x4 __attribute__((ext_vector_type(4)));
typedef short s16x8 __attribute__((ext_vector_type(8)));
typedef short s16x4 __attribute__((ext_vector_type(4)));
typedef __bf16 bf16x8 __attribute__((ext_vector_type(8)));

static __device__ __forceinline__ short f2bf(float f) {
    return __builtin_bit_cast(short, (__bf16)f);
}
static __device__ __forceinline__ float bf2f(short s) {
    union { unsigned u; float f; } v;
    v.u = ((unsigned)(unsigned short)s) << 16;
    return v.f;
}
static __device__ __forceinline__ f32x4 MM(s16x8 a, s16x8 b, f32x4 c) {
    return __builtin_amdgcn_mfma_f32_16x16x32_bf16(
        __builtin_bit_cast(bf16x8, a), __builtin_bit_cast(bf16x8, b), c, 0, 0, 0);
}

// ---------------------------------------------------------------------------
// K0: one-shot f32 -> bf16 conversion of all reused operands.
// ---------------------------------------------------------------------------
struct CvtArgs {
    const float* src[9];
    short* dst[9];
    unsigned n[9];
};

__global__ __launch_bounds__(256) void convert_kernel(CvtArgs a) {
    const int ai = blockIdx.y;
    const unsigned n = a.n[ai];
    const float* __restrict__ s = a.src[ai];
    short* __restrict__ d = a.dst[ai];
    const unsigned stride = gridDim.x * 256 * 8;
    for (unsigned base = (blockIdx.x * 256 + threadIdx.x) * 8; base < n; base += stride) {
        f32x4 v0 = *(const f32x4*)(s + base);
        f32x4 v1 = *(const f32x4*)(s + base + 4);
        s16x8 o;
        o[0] = f2bf(v0[0]); o[1] = f2bf(v0[1]); o[2] = f2bf(v0[2]); o[3] = f2bf(v0[3]);
        o[4] = f2bf(v1[0]); o[5] = f2bf(v1[1]); o[6] = f2bf(v1[2]); o[7] = f2bf(v1[3]);
        *(s16x8*)(d + base) = o;
    }
}

// ---------------------------------------------------------------------------
// K1: QKV projections, 64x64 wave tiles, swapped operands -> vector b64 stores.
// ---------------------------------------------------------------------------
__global__ __launch_bounds__(128, 2) void proj_kernel(
    const short* __restrict__ queryb, const short* __restrict__ keyb, const short* __restrict__ valueb,
    const short* __restrict__ Wqb, const float* __restrict__ bq,
    const short* __restrict__ Wkb, const float* __restrict__ bk,
    const short* __restrict__ Wvb, const float* __restrict__ bv,
    short* __restrict__ qb, short* __restrict__ kb, short* __restrict__ vT)
{
    const int tid = threadIdx.x;
    const int wid = tid >> 6, lane = tid & 63;
    const int l15 = lane & 15, grp = lane >> 4;
    const int gid = blockIdx.x * 2 + wid;     // 0..1535
    const int z = gid >> 9;                   // 0,1,2
    const int r = gid & 511;

    const short *Am, *Bm;
    const float* bias;
    int a0, b0;
    if (z == 0)      { Am = Wqb;    Bm = queryb; bias = bq; a0 = (r >> 6) * 64; b0 = (r & 63) * 64; }
    else if (z == 1) { Am = Wkb;    Bm = keyb;   bias = bk; a0 = (r >> 6) * 64; b0 = (r & 63) * 64; }
    else             { Am = valueb; Bm = Wvb;    bias = bv; a0 = (r >> 3) * 64; b0 = (r & 7) * 64; }

    f32x4 acc[4][4];
    #pragma unroll
    for (int i = 0; i < 4; ++i)
        #pragma unroll
        for (int j = 0; j < 4; ++j)
            acc[i][j] = f32x4{0.f, 0.f, 0.f, 0.f};

    const short* arow0 = Am + (size_t)(a0 + l15) * 512 + grp * 8;
    const short* brow0 = Bm + (size_t)(b0 + l15) * 512 + grp * 8;

    s16x8 aA[4], bA[4], aB[4], bB[4];
    #pragma unroll
    for (int i = 0; i < 4; ++i) {
        aA[i] = *(const s16x8*)(arow0 + (size_t)i * 16 * 512);
        bA[i] = *(const s16x8*)(brow0 + (size_t)i * 16 * 512);
    }
    for (int kk = 0; kk < 512; kk += 32) {
        const int kn = kk + 32;
        if (kn < 512) {
            #pragma unroll
            for (int i = 0; i < 4; ++i) {
                aB[i] = *(const s16x8*)(arow0 + (size_t)i * 16 * 512 + kn);
                bB[i] = *(const s16x8*)(brow0 + (size_t)i * 16 * 512 + kn);
            }
        }
        #pragma unroll
        for (int i = 0; i < 4; ++i)
            #pragma unroll
            for (int j = 0; j < 4; ++j)
                acc[i][j] = MM(aA[i], bA[j], acc[i][j]);
        #pragma unroll
        for (int i = 0; i < 4; ++i) { aA[i] = aB[i]; bA[i] = bB[i]; }
    }

    if (z < 2) {
        short* dst = (z == 0) ? qb : kb;
        #pragma unroll
        for (int i = 0; i < 4; ++i) {
            const int f0 = a0 + i * 16 + grp * 4;
            const f32x4 bv4 = *(const f32x4*)&bias[f0];
            const int h = f0 >> 6, d0 = f0 & 63;
            #pragma unroll
            for (int j = 0; j < 4; ++j) {
                const int srow = b0 + j * 16 + l15;
                const int bb = srow >> 10, sl = srow & 1023;
                s16x4 o;
                #pragma unroll
                for (int g = 0; g < 4; ++g)
                    o[g] = f2bf(acc[i][j][g] + bv4[g]);
                *(s16x4*)&dst[(size_t)((bb * 8 + h) * 1024 + sl) * 64 + d0] = o;
            }
        }
    } else {
        #pragma unroll
        for (int j = 0; j < 4; ++j) {
            const int n = b0 + j * 16 + l15;
            const float bval = bias[n];
            const int h = n >> 6, d = n & 63;
            #pragma unroll
            for (int i = 0; i < 4; ++i) {
                const int s0 = a0 + i * 16 + grp * 4;
                const int bb = s0 >> 10, sl = s0 & 1023;
                s16x4 o;
                #pragma unroll
                for (int g = 0; g < 4; ++g)
                    o[g] = f2bf(acc[i][j][g] + bval);
                *(s16x4*)&vT[(size_t)((bb * 8 + h) * 64 + d) * 1024 + sl] = o;
            }
        }
    }
}

// ---------------------------------------------------------------------------
// K2A: softmax + normalized attn write.  2048 blocks x 512 thr (8 waves).
// Block = (bh, 16-row strip); wave w owns cols [128w, 128w+128).
// Wave-private tables (no build barrier; same-wave LDS RAW is ordered):
//   LRQ [16][132] bf16 : LRQ[ii][jl] = q[ii].Eq[1023 + (128w+jl) - (i0+ii)]
//   LRB [16][36]  bf16 : LRB[ii][jql], jq = 32w+jql
//   LRR [16][8]   bf16 : LRR[ii][t],   jr = 8w+t
// LDS: 8*5632 + 512(RSUM) = 45568B.  One __syncthreads (RSUM).
// ---------------------------------------------------------------------------
__global__ __launch_bounds__(512, 4) void softmax_kernel(
    const short* __restrict__ Eqb, const short* __restrict__ Ebb, const short* __restrict__ Errb,
    const short* __restrict__ qb, const short* __restrict__ kb,
    float* __restrict__ attn)
{
    __shared__ __align__(16) char smem[45568];
    float* RSUM = (float*)(smem + 45056);      // [16][8]

    const int tid = threadIdx.x;
    const int wid = tid >> 6, lane = tid & 63;
    const int l15 = lane & 15, grp = lane >> 4;

    // XCD-aware bijective swizzle (2048 blocks, %8==0): XCD x -> 4 whole bh.
    const int orig = blockIdx.x;
    const int bid = (orig & 7) * 256 + (orig >> 3);

    const int bh = bid >> 6;                  // b*8+h
    const int i0 = (bid & 63) << 4;           // strip row base
    const int h = bh & 7;

    const short* EqH = Eqb  + (size_t)h * 2047 * 64;
    const short* EbH = Ebb  + (size_t)h * 511 * 64;
    const short* ErH = Errb + (size_t)h * 127 * 64;
    const short* qbH = qb + (size_t)bh * 1024 * 64;
    const short* kbH = kb + (size_t)bh * 1024 * 64;

    short* LRQ = (short*)(smem + wid * 5632);  // [16][132]
    short* LRB = LRQ + 16 * 132;               // [16][36]
    short* LRR = LRB + 16 * 36;                // [16][8]

    // q fragments (B-operand for build, n = i rows; B-operand for loop1 too)
    s16x8 q0 = *(const s16x8*)(qbH + (size_t)(i0 + l15) * 64 + grp * 8);
    s16x8 q1 = *(const s16x8*)(qbH + (size_t)(i0 + l15) * 64 + 32 + grp * 8);

    // ---- build LRQ: 10 tiles cover jl in [0,128) exactly once ----
    {
        const int E0 = 1023 - i0 + wid * 128 - 16;
        #pragma unroll 2
        for (int ck = 0; ck < 10; ++ck) {
            int erow = E0 + ck * 16 + l15;
            erow = erow < 0 ? 0 : (erow > 2046 ? 2046 : erow);
            const short* ep = EqH + (size_t)erow * 64 + grp * 8;
            s16x8 e0 = *(const s16x8*)ep;
            s16x8 e1 = *(const s16x8*)(ep + 32);
            f32x4 a = f32x4{0.f, 0.f, 0.f, 0.f};
            a = MM(q0, e0, a);
            a = MM(q1, e1, a);
            #pragma unroll
            for (int g = 0; g < 4; ++g) {
                const int ii = grp * 4 + g;
                const int jl = ck * 16 + l15 + ii - 16;
                if (jl >= 0 && jl < 128) LRQ[ii * 132 + jl] = f2bf(a[g]);
            }
        }
    }
    // ---- build LRB: 3 tiles cover jql in [0,32) ----
    {
        const int B0 = 255 - (i0 >> 2) + wid * 32 - 4;
        #pragma unroll
        for (int ck = 0; ck < 3; ++ck) {
            int erow = B0 + ck * 16 + l15;
            erow = erow < 0 ? 0 : (erow > 510 ? 510 : erow);
            const short* ep = EbH + (size_t)erow * 64 + grp * 8;
            s16x8 e0 = *(const s16x8*)ep;
            s16x8 e1 = *(const s16x8*)(ep + 32);
            f32x4 a = f32x4{0.f, 0.f, 0.f, 0.f};
            a = MM(q0, e0, a);
            a = MM(q1, e1, a);
            #pragma unroll
            for (int g = 0; g < 4; ++g) {
                const int ii = grp * 4 + g;
                const int jql = ck * 16 + l15 + (ii >> 2) - 4;
                if (jql >= 0 && jql < 32) LRB[ii * 36 + jql] = f2bf(a[g]);
            }
        }
    }
    // ---- build LRR: 1 tile, row uniform over ii (ii>>4 == 0) ----
    {
        const int R0 = 63 - (i0 >> 4) + wid * 8;
        int erow = R0 + l15;
        erow = erow > 126 ? 126 : erow;
        const short* ep = ErH + (size_t)erow * 64 + grp * 8;
        s16x8 e0 = *(const s16x8*)ep;
        s16x8 e1 = *(const s16x8*)(ep + 32);
        f32x4 a = f32x4{0.f, 0.f, 0.f, 0.f};
        a = MM(q0, e0, a);
        a = MM(q1, e1, a);
        if (l15 < 8) {
            #pragma unroll
            for (int g = 0; g < 4; ++g)
                LRR[(grp * 4 + g) * 8 + l15] = f2bf(a[g]);
        }
    }

    // ---- loop1: QK^T (swapped: MM(K,q) -> thread holds P[i=l15][4 cols]) ----
    const float SC = 0.125f * 1.4426950408889634f;   // 1/sqrt(64) * log2(e)
    f32x4 p[8];
    float part = 0.f;
    #pragma unroll
    for (int t = 0; t < 8; ++t) {
        const int jb = wid * 128 + t * 16;
        const short* kp = kbH + (size_t)(jb + l15) * 64 + grp * 8;
        s16x8 kf0 = *(const s16x8*)kp;
        s16x8 kf1 = *(const s16x8*)(kp + 32);
        f32x4 a = f32x4{0.f, 0.f, 0.f, 0.f};
        a = MM(kf0, q0, a);
        a = MM(kf1, q1, a);
        s16x4 gq4 = *(const s16x4*)&LRQ[l15 * 132 + t * 16 + grp * 4];
        const float rb = bf2f(LRB[l15 * 36 + t * 4 + grp]);
        const float rr = bf2f(LRR[l15 * 8 + t]);
        const float add = rb + rr;
        f32x4 pe;
        #pragma unroll
        for (int g = 0; g < 4; ++g) {
            pe[g] = __builtin_amdgcn_exp2f((a[g] + bf2f(gq4[g]) + add) * SC);
            part += pe[g];
        }
        p[t] = pe;
    }

    // ---- cross-grp rowsum partial -> RSUM; one barrier ----
    part += __shfl_xor(part, 16, 64);
    part += __shfl_xor(part, 32, 64);
    if (lane < 16) RSUM[lane * 8 + wid] = part;
    __syncthreads();

    float rinv;
    {
        f32x4 s0 = *(const f32x4*)&RSUM[l15 * 8];
        f32x4 s1 = *(const f32x4*)&RSUM[l15 * 8 + 4];
        rinv = 1.0f / (s0[0] + s0[1] + s0[2] + s0[3] + s1[0] + s1[1] + s1[2] + s1[3]);
    }

    // ---- normalized attn stores (regular stores; 64B segments per row) ----
    float* arow = attn + (size_t)(bh * 1024 + i0 + l15) * 1024;
    #pragma unroll
    for (int t = 0; t < 8; ++t) {
        f32x4 o = p[t] * rinv;
        *(f32x4*)&arow[wid * 128 + t * 16 + grp * 4] = o;
    }
}

// ---------------------------------------------------------------------------
// K2B: PV from attn (f32, L3-resident) x V -> out.  2048 blocks x 256 thr.
// Block = (bh, 16-row strip); wave w owns k-cols [256w, 256w+256) (split-K).
// LDS: PACC [4][16][68] f32 = 17408B.  One __syncthreads.
// ---------------------------------------------------------------------------
__global__ __launch_bounds__(256, 6) void pv_kernel(
    const float* __restrict__ attn, const short* __restrict__ vT,
    float* __restrict__ out)
{
    __shared__ __align__(16) float PACC[4 * 16 * 68];

    const int tid = threadIdx.x;
    const int wid = tid >> 6, lane = tid & 63;
    const int l15 = lane & 15, grp = lane >> 4;

    const int orig = blockIdx.x;
    const int bid = (orig & 7) * 256 + (orig >> 3);

    const int bh = bid >> 6;
    const int i0 = (bid & 63) << 4;
    const int h = bh & 7;
    const int b = bh >> 3;

    const float* aH = attn + (size_t)(bh * 1024 + i0 + l15) * 1024;
    const short* vTH = vT + (size_t)bh * 64 * 1024;

    const int c0 = wid * 256;
    f32x4 acc[4];
    #pragma unroll
    for (int dvt = 0; dvt < 4; ++dvt) acc[dvt] = f32x4{0.f, 0.f, 0.f, 0.f};

    #pragma unroll
    for (int kc = 0; kc < 8; ++kc) {
        const int col = c0 + kc * 32 + grp * 8;
        f32x4 a0 = *(const f32x4*)&aH[col];
        f32x4 a1 = *(const f32x4*)&aH[col + 4];
        s16x8 pfrag;
        #pragma unroll
        for (int g = 0; g < 4; ++g) { pfrag[g] = f2bf(a0[g]); pfrag[4 + g] = f2bf(a1[g]); }
        #pragma unroll
        for (int dvt = 0; dvt < 4; ++dvt) {
            s16x8 vfrag = *(const s16x8*)&vTH[(size_t)(dvt * 16 + l15) * 1024 + col];
            acc[dvt] = MM(vfrag, pfrag, acc[dvt]);
        }
    }

    #pragma unroll
    for (int dvt = 0; dvt < 4; ++dvt)
        *(f32x4*)&PACC[(wid * 16 + l15) * 68 + dvt * 16 + grp * 4] = acc[dvt];
    __syncthreads();

    // reduce 4 wave-partials; 256 threads -> (row i, 4 d's)
    const int i = tid >> 4, dq = tid & 15;
    f32x4 o = f32x4{0.f, 0.f, 0.f, 0.f};
    #pragma unroll
    for (int w = 0; w < 4; ++w)
        o += *(const f32x4*)&PACC[(w * 16 + i) * 68 + dq * 4];
    *(f32x4*)&out[(size_t)(b * 1024 + i0 + i) * 512 + h * 64 + dq * 4] = o;
}

// ---------------------------------------------------------------------------
extern "C" void kernel_launch(void* const* d_in, const int* in_sizes, int n_in,
                              void* d_out, int out_size, void* d_ws, size_t ws_size,
                              hipStream_t stream)
{
    const float* query = (const float*)d_in[0];
    const float* key   = (const float*)d_in[1];
    const float* value = (const float*)d_in[2];
    const float* Wq = (const float*)d_in[3];
    const float* bq = (const float*)d_in[4];
    const float* Wk = (const float*)d_in[5];
    const float* bk = (const float*)d_in[6];
    const float* Wv = (const float*)d_in[7];
    const float* bv = (const float*)d_in[8];
    const float* Eq = (const float*)d_in[9];
    const float* Eb = (const float*)d_in[10];
    const float* Er = (const float*)d_in[11];

    float* out  = (float*)d_out;
    float* attn = out + (size_t)4 * 1024 * 512;

    short* qb     = (short*)d_ws;
    short* kb     = qb     + 2097152;
    short* vT     = kb     + 2097152;
    short* queryb = vT     + 2097152;
    short* keyb   = queryb + 2097152;
    short* valueb = keyb   + 2097152;
    short* Wqb    = valueb + 2097152;
    short* Wkb    = Wqb    + 262144;
    short* Wvb    = Wkb    + 262144;
    short* Eqb    = Wvb    + 262144;
    short* Ebb    = Eqb    + 1048064;   // 8*2047*64
    short* Errb   = Ebb    + 261632;    // 8*511*64

    CvtArgs a;
    a.src[0] = query; a.dst[0] = queryb; a.n[0] = 2097152;
    a.src[1] = key;   a.dst[1] = keyb;   a.n[1] = 2097152;
    a.src[2] = value; a.dst[2] = valueb; a.n[2] = 2097152;
    a.src[3] = Wq;    a.dst[3] = Wqb;    a.n[3] = 262144;
    a.src[4] = Wk;    a.dst[4] = Wkb;    a.n[4] = 262144;
    a.src[5] = Wv;    a.dst[5] = Wvb;    a.n[5] = 262144;
    a.src[6] = Eq;    a.dst[6] = Eqb;    a.n[6] = 1048064;
    a.src[7] = Eb;    a.dst[7] = Ebb;    a.n[7] = 261632;
    a.src[8] = Er;    a.dst[8] = Errb;   a.n[8] = 65024;

    convert_kernel<<<dim3(128, 9), 256, 0, stream>>>(a);
    proj_kernel<<<768, 128, 0, stream>>>(queryb, keyb, valueb,
                                         Wqb, bq, Wkb, bk, Wvb, bv, qb, kb, vT);
    softmax_kernel<<<2048, 512, 0, stream>>>(Eqb, Ebb, Errb, qb, kb, attn);
    pv_kernel<<<2048, 256, 0, stream>>>(attn, vT, out);
}

// Round 11
// 157.244 us; speedup vs baseline: 1.4549x; 1.1801x over previous
//
#include <hip/hip_runtime.h>

// Multihead self-attention with 3-scale relative positional embeddings.
// B=4, S=1024, D=512, H=8, HD=64.  Outputs: out (4,1024,512) f32, attn (4,8,1024,1024) f32.
//
// Skew algebra (verified round 1):
//   Srel_q[i,j]  = q[i] . Er_q[1023 + j - i]
//   Srel_b[i,j]  = q[i] . Er_b[255 + (j>>2) - (i>>2)]
//   Srel_r[i,j]  = q[i] . Er_r[63  + (j>>4) - (i>>4)]
//
// Round-11: one fused kernel, 1 barrier, post-barrier wave specialization:
//   waves 0-3: PV full-K over private dv slice -> out (no reduce LDS)
//   waves 4-7: attn f32 stores, 1KB fully-contiguous per instruction, from PS
// PS = unnormalized bf16 P in the dead LRQ region (row-XOR swizzle).

typedef float f32x4 __attribute__((ext_vector_type(4)));
typedef short s16x8 __attribute__((ext_vector_type(8)));
typedef short s16x4 __attribute__((ext_vector_type(4)));
typedef __bf16 bf16x8 __attribute__((ext_vector_type(8)));

static __device__ __forceinline__ short f2bf(float f) {
    return __builtin_bit_cast(short, (__bf16)f);
}
static __device__ __forceinline__ float bf2f(short s) {
    union { unsigned u; float f; } v;
    v.u = ((unsigned)(unsigned short)s) << 16;
    return v.f;
}
static __device__ __forceinline__ f32x4 MM(s16x8 a, s16x8 b, f32x4 c) {
    return __builtin_amdgcn_mfma_f32_16x16x32_bf16(
        __builtin_bit_cast(bf16x8, a), __builtin_bit_cast(bf16x8, b), c, 0, 0, 0);
}

// ---------------------------------------------------------------------------
// K0: one-shot f32 -> bf16 conversion of all reused operands.
// ---------------------------------------------------------------------------
struct CvtArgs {
    const float* src[9];
    short* dst[9];
    unsigned n[9];
};

__global__ __launch_bounds__(256) void convert_kernel(CvtArgs a) {
    const int ai = blockIdx.y;
    const unsigned n = a.n[ai];
    const float* __restrict__ s = a.src[ai];
    short* __restrict__ d = a.dst[ai];
    const unsigned stride = gridDim.x * 256 * 8;
    for (unsigned base = (blockIdx.x * 256 + threadIdx.x) * 8; base < n; base += stride) {
        f32x4 v0 = *(const f32x4*)(s + base);
        f32x4 v1 = *(const f32x4*)(s + base + 4);
        s16x8 o;
        o[0] = f2bf(v0[0]); o[1] = f2bf(v0[1]); o[2] = f2bf(v0[2]); o[3] = f2bf(v0[3]);
        o[4] = f2bf(v1[0]); o[5] = f2bf(v1[1]); o[6] = f2bf(v1[2]); o[7] = f2bf(v1[3]);
        *(s16x8*)(d + base) = o;
    }
}

// ---------------------------------------------------------------------------
// K1: QKV projections, 64x64 wave tiles, swapped operands -> vector b64 stores.
// ---------------------------------------------------------------------------
__global__ __launch_bounds__(128, 2) void proj_kernel(
    const short* __restrict__ queryb, const short* __restrict__ keyb, const short* __restrict__ valueb,
    const short* __restrict__ Wqb, const float* __restrict__ bq,
    const short* __restrict__ Wkb, const float* __restrict__ bk,
    const short* __restrict__ Wvb, const float* __restrict__ bv,
    short* __restrict__ qb, short* __restrict__ kb, short* __restrict__ vT)
{
    const int tid = threadIdx.x;
    const int wid = tid >> 6, lane = tid & 63;
    const int l15 = lane & 15, grp = lane >> 4;
    const int gid = blockIdx.x * 2 + wid;     // 0..1535
    const int z = gid >> 9;                   // 0,1,2
    const int r = gid & 511;

    const short *Am, *Bm;
    const float* bias;
    int a0, b0;
    if (z == 0)      { Am = Wqb;    Bm = queryb; bias = bq; a0 = (r >> 6) * 64; b0 = (r & 63) * 64; }
    else if (z == 1) { Am = Wkb;    Bm = keyb;   bias = bk; a0 = (r >> 6) * 64; b0 = (r & 63) * 64; }
    else             { Am = valueb; Bm = Wvb;    bias = bv; a0 = (r >> 3) * 64; b0 = (r & 7) * 64; }

    f32x4 acc[4][4];
    #pragma unroll
    for (int i = 0; i < 4; ++i)
        #pragma unroll
        for (int j = 0; j < 4; ++j)
            acc[i][j] = f32x4{0.f, 0.f, 0.f, 0.f};

    const short* arow0 = Am + (size_t)(a0 + l15) * 512 + grp * 8;
    const short* brow0 = Bm + (size_t)(b0 + l15) * 512 + grp * 8;

    s16x8 aA[4], bA[4], aB[4], bB[4];
    #pragma unroll
    for (int i = 0; i < 4; ++i) {
        aA[i] = *(const s16x8*)(arow0 + (size_t)i * 16 * 512);
        bA[i] = *(const s16x8*)(brow0 + (size_t)i * 16 * 512);
    }
    for (int kk = 0; kk < 512; kk += 32) {
        const int kn = kk + 32;
        if (kn < 512) {
            #pragma unroll
            for (int i = 0; i < 4; ++i) {
                aB[i] = *(const s16x8*)(arow0 + (size_t)i * 16 * 512 + kn);
                bB[i] = *(const s16x8*)(brow0 + (size_t)i * 16 * 512 + kn);
            }
        }
        #pragma unroll
        for (int i = 0; i < 4; ++i)
            #pragma unroll
            for (int j = 0; j < 4; ++j)
                acc[i][j] = MM(aA[i], bA[j], acc[i][j]);
        #pragma unroll
        for (int i = 0; i < 4; ++i) { aA[i] = aB[i]; bA[i] = bB[i]; }
    }

    if (z < 2) {
        short* dst = (z == 0) ? qb : kb;
        #pragma unroll
        for (int i = 0; i < 4; ++i) {
            const int f0 = a0 + i * 16 + grp * 4;
            const f32x4 bv4 = *(const f32x4*)&bias[f0];
            const int h = f0 >> 6, d0 = f0 & 63;
            #pragma unroll
            for (int j = 0; j < 4; ++j) {
                const int srow = b0 + j * 16 + l15;
                const int bb = srow >> 10, sl = srow & 1023;
                s16x4 o;
                #pragma unroll
                for (int g = 0; g < 4; ++g)
                    o[g] = f2bf(acc[i][j][g] + bv4[g]);
                *(s16x4*)&dst[(size_t)((bb * 8 + h) * 1024 + sl) * 64 + d0] = o;
            }
        }
    } else {
        #pragma unroll
        for (int j = 0; j < 4; ++j) {
            const int n = b0 + j * 16 + l15;
            const float bval = bias[n];
            const int h = n >> 6, d = n & 63;
            #pragma unroll
            for (int i = 0; i < 4; ++i) {
                const int s0 = a0 + i * 16 + grp * 4;
                const int bb = s0 >> 10, sl = s0 & 1023;
                s16x4 o;
                #pragma unroll
                for (int g = 0; g < 4; ++g)
                    o[g] = f2bf(acc[i][j][g] + bval);
                *(s16x4*)&vT[(size_t)((bb * 8 + h) * 64 + d) * 1024 + sl] = o;
            }
        }
    }
}

// ---------------------------------------------------------------------------
// K2: fused softmax + PV + attn store.  2048 blocks x 512 thr (8 waves).
// Block = (bh, 16-row strip); pre-barrier wave w owns cols [128w,128w+128).
// Wave region (5760B each): LRQ[16][136] bf16 (reused as PS[16][128] with
// row-XOR swizzle), LRB[16][36], LRR[16][8].  RSUM[16][8] f32 at 46080.
// LDS 46592B -> 2 blocks/CU.  ONE barrier.
// Post-barrier: waves 0-3 PV (dv slice 16w..16w+16, full K=1024) -> out;
//               waves 4-7 store attn f32 (1KB contiguous per instruction).
// ---------------------------------------------------------------------------
__global__ __launch_bounds__(512, 4) void attn_fused(
    const short* __restrict__ Eqb, const short* __restrict__ Ebb, const short* __restrict__ Errb,
    const short* __restrict__ qb, const short* __restrict__ kb, const short* __restrict__ vT,
    float* __restrict__ out, float* __restrict__ attn)
{
    __shared__ __align__(16) char smem[46592];
    float* RSUM = (float*)(smem + 46080);      // [16][8]
    const int WR = 5760;                       // wave region bytes

    const int tid = threadIdx.x;
    const int wid = tid >> 6, lane = tid & 63;
    const int l15 = lane & 15, grp = lane >> 4;

    // XCD-aware bijective swizzle (2048 blocks, %8==0): XCD x -> 4 whole bh.
    const int orig = blockIdx.x;
    const int bid = (orig & 7) * 256 + (orig >> 3);

    const int bh = bid >> 6;                  // b*8+h
    const int i0 = (bid & 63) << 4;           // strip row base
    const int h = bh & 7;
    const int b = bh >> 3;

    const short* EqH = Eqb  + (size_t)h * 2047 * 64;
    const short* EbH = Ebb  + (size_t)h * 511 * 64;
    const short* ErH = Errb + (size_t)h * 127 * 64;
    const short* qbH = qb + (size_t)bh * 1024 * 64;
    const short* kbH = kb + (size_t)bh * 1024 * 64;
    const short* vTH = vT + (size_t)bh * 64 * 1024;

    short* LRQ = (short*)(smem + wid * WR);    // [16][136]
    short* LRB = LRQ + 16 * 136;               // [16][36]
    short* LRR = LRB + 16 * 36;                // [16][8]

    // q fragments
    s16x8 q0 = *(const s16x8*)(qbH + (size_t)(i0 + l15) * 64 + grp * 8);
    s16x8 q1 = *(const s16x8*)(qbH + (size_t)(i0 + l15) * 64 + 32 + grp * 8);

    // ---- build LRQ: 10 tiles, 2-deep pipelined Er loads ----
    {
        const int E0 = 1023 - i0 + wid * 128 - 16;
        auto ldq = [&](int ck, s16x8& e0, s16x8& e1) {
            int erow = E0 + ck * 16 + l15;
            erow = erow < 0 ? 0 : (erow > 2046 ? 2046 : erow);
            const short* ep = EqH + (size_t)erow * 64 + grp * 8;
            e0 = *(const s16x8*)ep;
            e1 = *(const s16x8*)(ep + 32);
        };
        s16x8 A0, A1, B0, B1;
        ldq(0, A0, A1);
        ldq(1, B0, B1);
        for (int ck = 0; ck < 10; ++ck) {
            f32x4 a = f32x4{0.f, 0.f, 0.f, 0.f};
            a = MM(q0, A0, a);
            a = MM(q1, A1, a);
            A0 = B0; A1 = B1;
            if (ck < 8) ldq(ck + 2, B0, B1);
            #pragma unroll
            for (int g = 0; g < 4; ++g) {
                const int ii = grp * 4 + g;
                const int jl = ck * 16 + l15 + ii - 16;
                if (jl >= 0 && jl < 128) LRQ[ii * 136 + jl] = f2bf(a[g]);
            }
        }
    }
    // ---- build LRB: 3 tiles ----
    {
        const int B0i = 255 - (i0 >> 2) + wid * 32 - 4;
        #pragma unroll
        for (int ck = 0; ck < 3; ++ck) {
            int erow = B0i + ck * 16 + l15;
            erow = erow < 0 ? 0 : (erow > 510 ? 510 : erow);
            const short* ep = EbH + (size_t)erow * 64 + grp * 8;
            s16x8 e0 = *(const s16x8*)ep;
            s16x8 e1 = *(const s16x8*)(ep + 32);
            f32x4 a = f32x4{0.f, 0.f, 0.f, 0.f};
            a = MM(q0, e0, a);
            a = MM(q1, e1, a);
            #pragma unroll
            for (int g = 0; g < 4; ++g) {
                const int ii = grp * 4 + g;
                const int jql = ck * 16 + l15 + (ii >> 2) - 4;
                if (jql >= 0 && jql < 32) LRB[ii * 36 + jql] = f2bf(a[g]);
            }
        }
    }
    // ---- build LRR: 1 tile ----
    {
        const int R0 = 63 - (i0 >> 4) + wid * 8;
        int erow = R0 + l15;
        erow = erow > 126 ? 126 : erow;
        const short* ep = ErH + (size_t)erow * 64 + grp * 8;
        s16x8 e0 = *(const s16x8*)ep;
        s16x8 e1 = *(const s16x8*)(ep + 32);
        f32x4 a = f32x4{0.f, 0.f, 0.f, 0.f};
        a = MM(q0, e0, a);
        a = MM(q1, e1, a);
        if (l15 < 8) {
            #pragma unroll
            for (int g = 0; g < 4; ++g)
                LRR[(grp * 4 + g) * 8 + l15] = f2bf(a[g]);
        }
    }

    // ---- loop1: QK^T (swapped) + gathers + exp2 -> p (unnormalized) ----
    const float SC = 0.125f * 1.4426950408889634f;   // 1/sqrt(64) * log2(e)
    f32x4 p[8];
    float part = 0.f;
    #pragma unroll
    for (int t = 0; t < 8; ++t) {
        const int jb = wid * 128 + t * 16;
        const short* kp = kbH + (size_t)(jb + l15) * 64 + grp * 8;
        s16x8 kf0 = *(const s16x8*)kp;
        s16x8 kf1 = *(const s16x8*)(kp + 32);
        f32x4 a = f32x4{0.f, 0.f, 0.f, 0.f};
        a = MM(kf0, q0, a);
        a = MM(kf1, q1, a);
        s16x4 gq4 = *(const s16x4*)&LRQ[l15 * 136 + t * 16 + grp * 4];
        const float rb = bf2f(LRB[l15 * 36 + t * 4 + grp]);
        const float rr = bf2f(LRR[l15 * 8 + t]);
        const float add = rb + rr;
        f32x4 pe;
        #pragma unroll
        for (int g = 0; g < 4; ++g) {
            pe[g] = __builtin_amdgcn_exp2f((a[g] + bf2f(gq4[g]) + add) * SC);
            part += pe[g];
        }
        p[t] = pe;
    }

    // ---- rowsum partial -> RSUM ----
    part += __shfl_xor(part, 16, 64);
    part += __shfl_xor(part, 32, 64);
    if (lane < 16) RSUM[lane * 8 + wid] = part;

    // ---- stage unnormalized bf16 P over dead LRQ (row-XOR swizzle) ----
    {
        char* wr = smem + wid * WR + l15 * 272;
        const int sw = (l15 & 3) << 4;
        #pragma unroll
        for (int t = 0; t < 8; ++t) {
            s16x4 o;
            #pragma unroll
            for (int g = 0; g < 4; ++g) o[g] = f2bf(p[t][g]);
            *(s16x4*)(wr + ((t * 32 + grp * 8) ^ sw)) = o;
        }
    }
    __syncthreads();                           // the ONE barrier

    if (wid < 4) {
        // ---- PV: dv slice [16*wid, 16*wid+16), full K=1024 ----
        float rinv;
        {
            f32x4 s0 = *(const f32x4*)&RSUM[l15 * 8];
            f32x4 s1 = *(const f32x4*)&RSUM[l15 * 8 + 4];
            rinv = 1.0f / (s0[0] + s0[1] + s0[2] + s0[3] + s1[0] + s1[1] + s1[2] + s1[3]);
        }
        const int sw = (l15 & 3) << 4;
        const char* psbase = smem + l15 * 272;
        const short* vbase = vTH + (size_t)(wid * 16 + l15) * 1024 + grp * 8;
        f32x4 acc = f32x4{0.f, 0.f, 0.f, 0.f};
        s16x8 vA = *(const s16x8*)(vbase);
        s16x8 vB = *(const s16x8*)(vbase + 32);
        for (int kt = 0; kt < 32; ++kt) {
            s16x8 vcur = vA;
            vA = vB;
            if (kt < 30) vB = *(const s16x8*)(vbase + (size_t)(kt + 2) * 32);
            const char* rg = psbase + (kt >> 2) * WR;
            s16x8 bf = *(const s16x8*)(rg + ((((kt & 3) * 64 + grp * 16) ^ sw)));
            acc = MM(vcur, bf, acc);
        }
        acc *= rinv;
        *(f32x4*)&out[(size_t)(b * 1024 + i0 + l15) * 512 + h * 64 + wid * 16 + grp * 4] = acc;
    } else {
        // ---- attn store: 2 col-slices (256 cols) per wave, 1KB/instruction ----
        const int s2 = wid - 4;
        const int colg = s2 * 256 + lane * 4;
        const char* rg = smem + (colg >> 7) * WR;
        const int cin = (lane & 31) * 8;       // byte offset of 4 bf16 within row
        float* abase = attn + (size_t)(bh * 1024 + i0) * 1024 + colg;
        #pragma unroll 4
        for (int r = 0; r < 16; ++r) {
            f32x4 s0 = *(const f32x4*)&RSUM[r * 8];
            f32x4 s1 = *(const f32x4*)&RSUM[r * 8 + 4];
            const float ri = 1.0f / (s0[0] + s0[1] + s0[2] + s0[3] + s1[0] + s1[1] + s1[2] + s1[3]);
            s16x4 v4 = *(const s16x4*)(rg + r * 272 + (cin ^ ((r & 3) << 4)));
            f32x4 o;
            o[0] = bf2f(v4[0]) * ri; o[1] = bf2f(v4[1]) * ri;
            o[2] = bf2f(v4[2]) * ri; o[3] = bf2f(v4[3]) * ri;
            *(f32x4*)(abase + (size_t)r * 1024) = o;
        }
    }
}

// ---------------------------------------------------------------------------
extern "C" void kernel_launch(void* const* d_in, const int* in_sizes, int n_in,
                              void* d_out, int out_size, void* d_ws, size_t ws_size,
                              hipStream_t stream)
{
    const float* query = (const float*)d_in[0];
    const float* key   = (const float*)d_in[1];
    const float* value = (const float*)d_in[2];
    const float* Wq = (const float*)d_in[3];
    const float* bq = (const float*)d_in[4];
    const float* Wk = (const float*)d_in[5];
    const float* bk = (const float*)d_in[6];
    const float* Wv = (const float*)d_in[7];
    const float* bv = (const float*)d_in[8];
    const float* Eq = (const float*)d_in[9];
    const float* Eb = (const float*)d_in[10];
    const float* Er = (const float*)d_in[11];

    float* out  = (float*)d_out;
    float* attn = out + (size_t)4 * 1024 * 512;

    short* qb     = (short*)d_ws;
    short* kb     = qb     + 2097152;
    short* vT     = kb     + 2097152;
    short* queryb = vT     + 2097152;
    short* keyb   = queryb + 2097152;
    short* valueb = keyb   + 2097152;
    short* Wqb    = valueb + 2097152;
    short* Wkb    = Wqb    + 262144;
    short* Wvb    = Wkb    + 262144;
    short* Eqb    = Wvb    + 262144;
    short* Ebb    = Eqb    + 1048064;   // 8*2047*64
    short* Errb   = Ebb    + 261632;    // 8*511*64

    CvtArgs a;
    a.src[0] = query; a.dst[0] = queryb; a.n[0] = 2097152;
    a.src[1] = key;   a.dst[1] = keyb;   a.n[1] = 2097152;
    a.src[2] = value; a.dst[2] = valueb; a.n[2] = 2097152;
    a.src[3] = Wq;    a.dst[3] = Wqb;    a.n[3] = 262144;
    a.src[4] = Wk;    a.dst[4] = Wkb;    a.n[4] = 262144;
    a.src[5] = Wv;    a.dst[5] = Wvb;    a.n[5] = 262144;
    a.src[6] = Eq;    a.dst[6] = Eqb;    a.n[6] = 1048064;
    a.src[7] = Eb;    a.dst[7] = Ebb;    a.n[7] = 261632;
    a.src[8] = Er;    a.dst[8] = Errb;   a.n[8] = 65024;

    convert_kernel<<<dim3(128, 9), 256, 0, stream>>>(a);
    proj_kernel<<<768, 128, 0, stream>>>(queryb, keyb, valueb,
                                         Wqb, bq, Wkb, bk, Wvb, bv, qb, kb, vT);
    attn_fused<<<2048, 512, 0, stream>>>(Eqb, Ebb, Errb, qb, kb, vT, out, attn);
}